// Round 10
// baseline (2730.004 us; speedup 1.0000x reference)
//
#include <hip/hip_runtime.h>
#include <hip/hip_bf16.h>
#include <math.h>

// Problem constants
#define BQ 8
#define C1N 512
#define N1 784          // 28*28
#define C2N 1024
#define M2 196          // 14*14
#define NROWS 6272      // 8*784
#define NROWSP 6400     // 25*256 (padded)
#define NTA 25          // A tiles of 256 rows
#define MEMN 20000
#define MEMNP 20224     // 79*256 (padded)
#define NTB 79          // B tiles of 256 rows
#define DIMK 1024
#define NKB 32          // K blocks of 32
#define KTE 8192        // elems per K-block per 256-row tile (4*256*8)
#define OUTHW 50176     // 224*224
#define NWG (NTA * NTB) // 1975

typedef unsigned short u16;
typedef __attribute__((ext_vector_type(8))) short short8v;
typedef __attribute__((ext_vector_type(4))) float f32x4;

// ---- order-preserving float <-> uint for atomicMin ----
static __device__ __forceinline__ unsigned int f2ord(float f) {
  unsigned int b = __float_as_uint(f);
  return (b & 0x80000000u) ? ~b : (b | 0x80000000u);
}
static __device__ __forceinline__ float ord2f(unsigned int u) {
  unsigned int b = (u & 0x80000000u) ? (u ^ 0x80000000u) : ~u;
  return __uint_as_float(b);
}

// ---- bf16 helpers (RNE) ----
static __device__ __forceinline__ u16 f2bf(float x) {
  unsigned u = __float_as_uint(x);
  u += 0x7FFFu + ((u >> 16) & 1u);
  return (u16)(u >> 16);
}
static __device__ __forceinline__ float bf2f(u16 b) {
  return __uint_as_float(((unsigned)b) << 16);
}

// ---- async global->LDS (16B per lane; LDS dest = wave-uniform base + lane*16) ----
static __device__ __forceinline__ void gload16(const void* g, void* l) {
  __builtin_amdgcn_global_load_lds((const __attribute__((address_space(1))) void*)g,
                                   (__attribute__((address_space(3))) void*)l, 16, 0, 0);
}

// ---- tiled (k-major) element index, 256-row tiles ----
// layout: [tile][kb=32][c=4][row=256][e=8] ; element (grow=tile*256+row, k=kb*32+c*8+e)
static __device__ __forceinline__ size_t tiled_idx(int grow, int k) {
  int tile = grow >> 8, row = grow & 255;
  int kb = k >> 5, c = (k >> 3) & 3, e = k & 7;
  return (((size_t)(tile * NKB + kb) * 4 + c) * 256 + row) * 8 + e;
}

// ---- scrambled patchify flat-index decode ----
// Reference's patchify flattens per-batch in (kj, w, c, ki, h) row-major order:
//   L = (((kj*W + w)*C + c)*3 + ki)*H + h ; value = x[b, c, h+ki-1, w+kj-1] (0 if OOB)
static __device__ __forceinline__ float f1val(const float* __restrict__ x, int b, unsigned L) {
  unsigned h = L % 28u; unsigned t = L / 28u;
  unsigned ki = t % 3u; t /= 3u;
  unsigned c = t % 512u; t /= 512u;
  unsigned w = t % 28u; unsigned kj = t / 28u;
  unsigned y = h + ki - 1u;   // wraps to huge if -1
  unsigned xx = w + kj - 1u;
  if (y >= 28u || xx >= 28u) return 0.f;
  return x[(((size_t)b * 512u + c) * 28u + y) * 28u + xx];
}
static __device__ __forceinline__ float f2val(const float* __restrict__ x, int b, unsigned L) {
  unsigned h = L % 14u; unsigned t = L / 14u;
  unsigned ki = t % 3u; t /= 3u;
  unsigned c = t % 1024u; t /= 1024u;
  unsigned w = t % 14u; unsigned kj = t / 14u;
  unsigned y = h + ki - 1u;
  unsigned xx = w + kj - 1u;
  if (y >= 14u || xx >= 14u) return 0.f;
  return x[(((size_t)b * 1024u + c) * 14u + y) * 14u + xx];
}

// feats[b,n,j<512] = (sum_{u=0..8} F1[9*(512n+j)+u] + F1[...+4]) / 10  -> tiled layout
__global__ __launch_bounds__(256) void feat_a_bf(const float* __restrict__ feat1,
                                                 u16* __restrict__ At) {
  int id = blockIdx.x * 256 + threadIdx.x;
  if (id >= BQ * N1 * C1N) return;
  int j = id & 511; int t = id >> 9;
  int n = t % N1; int b = t / N1;
  unsigned L0 = 9u * (unsigned)(512 * n + j);
  float s = 0.f;
#pragma unroll
  for (int u = 0; u < 9; ++u) s += f1val(feat1, b, L0 + u);
  s += f1val(feat1, b, L0 + 4u);
  At[tiled_idx(b * N1 + n, j)] = f2bf(s * 0.1f);
}

// H2all[b][n2][i] = (1/18) sum_{u<18} F2[18*(512*n2+i)+u]
__global__ __launch_bounds__(256) void feat_b_stage1(const float* __restrict__ feat2,
                                                     float* __restrict__ H2all) {
  int b = blockIdx.x / M2;
  int n2 = blockIdx.x % M2;
  for (int i = threadIdx.x; i < 512; i += 256) {
    unsigned L0 = 18u * (unsigned)(512 * n2 + i);
    float s = 0.f;
#pragma unroll
    for (int u = 0; u < 18; ++u) s += f2val(feat2, b, L0 + u);
    H2all[((size_t)b * M2 + n2) * 512 + i] = s * (1.0f / 18.0f);
  }
}

// bilinear 14x14 -> 28x28 over the n2 grid, write feats[b,n,512+i] -> tiled layout
__global__ __launch_bounds__(256) void feat_b_stage2(const float* __restrict__ H2all,
                                                     u16* __restrict__ At) {
  int bn = blockIdx.x;
  int b = bn / N1, n = bn % N1;
  int y = n / 28, x = n % 28;
  float sy = 0.5f * (float)y - 0.25f;
  sy = fminf(fmaxf(sy, 0.f), 13.f);
  int y0 = (int)sy, y1 = min(y0 + 1, 13);
  float wy = sy - (float)y0;
  float sx = 0.5f * (float)x - 0.25f;
  sx = fminf(fmaxf(sx, 0.f), 13.f);
  int x0 = (int)sx, x1 = min(x0 + 1, 13);
  float wx = sx - (float)x0;
  float w00 = (1.f - wy) * (1.f - wx), w10 = wy * (1.f - wx);
  float w01 = (1.f - wy) * wx, w11 = wy * wx;
  const float* h00 = H2all + ((size_t)b * M2 + y0 * 14 + x0) * 512;
  const float* h10 = H2all + ((size_t)b * M2 + y1 * 14 + x0) * 512;
  const float* h01 = H2all + ((size_t)b * M2 + y0 * 14 + x1) * 512;
  const float* h11 = H2all + ((size_t)b * M2 + y1 * 14 + x1) * 512;
  for (int i = threadIdx.x; i < 512; i += 256) {
    float v = w00 * h00[i] + w10 * h10[i] + w01 * h01[i] + w11 * h11[i];
    At[tiled_idx(bn, 512 + i)] = f2bf(v);
  }
}

// memory fp32 -> bf16 tiled; rows [MEMN, MEMNP) = 0. One 8-elem unit per thread,
// dst linear in thread id -> coalesced writes.
__global__ __launch_bounds__(256) void memconv(const float* __restrict__ mem,
                                               u16* __restrict__ Bt) {
  int gid = blockIdx.x * 256 + threadIdx.x;
  if (gid >= NTB * NKB * 1024) return;
  int tile = gid >> 15;            // 32*1024 units per tile
  int within = gid & 32767;
  int kb = within >> 10;
  int u = within & 1023;
  int c = u >> 8, row = u & 255;
  int n = tile * 256 + row;
  int k0 = kb * 32 + c * 8;
  short8v o;
  if (n < MEMN) {
    const float* src = mem + (size_t)n * DIMK + k0;
    float4 a = *(const float4*)src;
    float4 b = *(const float4*)(src + 4);
    o[0] = (short)f2bf(a.x); o[1] = (short)f2bf(a.y);
    o[2] = (short)f2bf(a.z); o[3] = (short)f2bf(a.w);
    o[4] = (short)f2bf(b.x); o[5] = (short)f2bf(b.y);
    o[6] = (short)f2bf(b.z); o[7] = (short)f2bf(b.w);
  } else {
#pragma unroll
    for (int i = 0; i < 8; ++i) o[i] = 0;
  }
  *(short8v*)&Bt[(size_t)gid * 8] = o;
}

// fnorm from tiled bf16 feats: 1 wave per row
__global__ __launch_bounds__(256) void fnorm_bf(const u16* __restrict__ At,
                                                float* __restrict__ fnorm) {
  int row = blockIdx.x * 4 + (threadIdx.x >> 6);
  int lane = threadIdx.x & 63;
  float s = 0.f;
#pragma unroll
  for (int q = 0; q < 2; ++q) {
    int k = (lane + q * 64) * 8;
    short8v v = *(const short8v*)&At[tiled_idx(row, k)];
#pragma unroll
    for (int i = 0; i < 8; ++i) {
      float f = bf2f((u16)v[i]);
      s = fmaf(f, f, s);
    }
  }
#pragma unroll
  for (int off = 32; off; off >>= 1) s += __shfl_down(s, off, 64);
  if (lane == 0) fnorm[row] = s;
}

__global__ __launch_bounds__(256) void mnorm_kernel(const float* __restrict__ memory,
                                                    float* __restrict__ mnorm) {
  __shared__ float red[4];
  const int row = blockIdx.x;
  const float4 v = *(const float4*)&memory[(size_t)row * DIMK + threadIdx.x * 4];
  float s = v.x * v.x + v.y * v.y + v.z * v.z + v.w * v.w;
#pragma unroll
  for (int off = 32; off; off >>= 1) s += __shfl_down(s, off, 64);
  if ((threadIdx.x & 63) == 0) red[threadIdx.x >> 6] = s;
  __syncthreads();
  if (threadIdx.x == 0) mnorm[row] = red[0] + red[1] + red[2] + red[3];
}

// ---- bf16 MFMA distance GEMM + row-min ----
// 256x256 tile, BK=32, 8 waves (2Mx4N, per-wave 128x64), 2 LDS slots (64 KB total
// -> 2 blocks/CU). 1-deep counted pipeline per K-tile:
//   STAGE(tile T+1 -> slot S^1) ; vmcnt(4) [drains tile T, issued a full step ago]
//   ; s_barrier ; 12 ds_read_b128 + 32 MFMA (setprio) ; s_barrier.
// vmcnt never drains to 0 in the main loop. Overlap comes from 2 independent
// blocks per CU (round-5 mechanism) with 256^2's better LDS-traffic/FLOP.
__global__ __launch_bounds__(512, 4) void dist_min_mfma(const u16* __restrict__ At,
                                                        const u16* __restrict__ Bt,
                                                        const float* __restrict__ mnorm,
                                                        unsigned int* __restrict__ minu) {
  __shared__ __align__(16) u16 LA[2][8192];   // [slot][c4 x row256 x e8] = 16 KB
  __shared__ __align__(16) u16 LB[2][8192];
  const int t = threadIdx.x;
  const int wave = t >> 6, lane = t & 63;

  // bijective XCD chunking (m204): q=246, r=7
  int lid = blockIdx.x;
  const int q = NWG / 8, r = NWG % 8;
  int xcd = lid & 7, pos = lid >> 3;
  int wgid = (xcd < r ? xcd * (q + 1) : r * (q + 1) + (xcd - r) * q) + pos;
  // supertile: 5 row-tiles per group (25 = 5*5), rows fastest within a column
  int g = wgid / (NTB * 5), rem = wgid % (NTB * 5);
  int bx = rem / 5;            // col tile 0..78
  int by = g * 5 + rem % 5;    // row tile 0..24
  const int row0 = by * 256, col0 = bx * 256;

  f32x4 acc[8][4];
#pragma unroll
  for (int i = 0; i < 8; ++i)
#pragma unroll
    for (int j = 0; j < 4; ++j) acc[i][j] = (f32x4){0.f, 0.f, 0.f, 0.f};

  const int wr = (wave >> 2) * 128, wc = (wave & 3) * 64;
  const int frow = lane & 15, fc = lane >> 4;
  const int aoff = fc * 2048 + (wr + frow) * 8;   // + mi*128 elems
  const int boff = fc * 2048 + (wc + frow) * 8;   // + ni*128 elems
  const int so = wave * 512 + lane * 8;           // staging slice (4096 elems/round)

  const u16* aG = At + (size_t)by * (NKB * KTE) + so;
  const u16* bG = Bt + (size_t)bx * (NKB * KTE) + so;

  // stage one K-tile (A 16KB + B 16KB) into slot buf; advance pointers
#define STAGE(buf)                                   \
  do {                                               \
    gload16(aG,        &LA[buf][wave * 512]);        \
    gload16(aG + 4096, &LA[buf][4096 + wave * 512]); \
    gload16(bG,        &LB[buf][wave * 512]);        \
    gload16(bG + 4096, &LB[buf][4096 + wave * 512]); \
    aG += KTE; bG += KTE;                            \
  } while (0)

#define SPRIO1 __builtin_amdgcn_s_setprio(1)
#define SPRIO0 __builtin_amdgcn_s_setprio(0)
#define SBAR __builtin_amdgcn_s_barrier()
#define VMW4 asm volatile("s_waitcnt vmcnt(4)" ::: "memory")
#define VMW0 asm volatile("s_waitcnt vmcnt(0)" ::: "memory")

  // one K-tile: compute slot S; if STG, stage next tile into S^1 first
#define STEP(S, STG)                                                                         \
  do {                                                                                       \
    if (STG) { STAGE((S) ^ 1); VMW4; } else { VMW0; }                                        \
    SBAR;                                                                                    \
    short8v a[8], b[4];                                                                      \
    _Pragma("unroll") for (int mi = 0; mi < 8; ++mi)                                         \
        a[mi] = *(const short8v*)&LA[S][aoff + mi * 128];                                    \
    _Pragma("unroll") for (int ni = 0; ni < 4; ++ni)                                         \
        b[ni] = *(const short8v*)&LB[S][boff + ni * 128];                                    \
    SPRIO1;                                                                                  \
    _Pragma("unroll") for (int mi = 0; mi < 8; ++mi)                                         \
      _Pragma("unroll") for (int ni = 0; ni < 4; ++ni)                                       \
          acc[mi][ni] = __builtin_amdgcn_mfma_f32_16x16x32_bf16(a[mi], b[ni], acc[mi][ni],   \
                                                                0, 0, 0);                    \
    SPRIO0;                                                                                  \
    SBAR;                                                                                    \
  } while (0)

  // prologue: tile 0 into slot 0, drain, sync
  STAGE(0);
  VMW0;
  SBAR;

  // 32 K-tiles: 15 pairs (tiles 0..29), tile 30 (stages 31), tile 31 (drain)
#pragma unroll 1
  for (int i = 0; i < 15; ++i) {
    STEP(0, true);
    STEP(1, true);
  }
  STEP(0, true);    // tile 30, stages tile 31 into slot 1
  STEP(1, false);   // tile 31, drain variant
#undef STEP
#undef STAGE

  // epilogue: v = mnorm[col] - 2*dot ; row-min across the 16-lane group
  float cmn[4];
#pragma unroll
  for (int ni = 0; ni < 4; ++ni) {
    int gn = col0 + wc + ni * 16 + frow;
    cmn[ni] = (gn < MEMN) ? mnorm[gn] : INFINITY;
  }
#pragma unroll
  for (int mi = 0; mi < 8; ++mi) {
#pragma unroll
    for (int rr = 0; rr < 4; ++rr) {
      float v = INFINITY;
#pragma unroll
      for (int ni = 0; ni < 4; ++ni)
        v = fminf(v, fmaf(-2.f, acc[mi][ni][rr], cmn[ni]));
#pragma unroll
      for (int off = 1; off < 16; off <<= 1)
        v = fminf(v, __shfl_xor(v, off, 64));
      if (frow == 0) {
        int grow = row0 + wr + mi * 16 + fc * 4 + rr;
        atomicMin(&minu[grow], f2ord(v));
      }
    }
  }
}

// ================= epilogue kernels =================

__global__ __launch_bounds__(256) void scores_kernel(const float* __restrict__ fnorm,
                                                     const unsigned int* __restrict__ minu,
                                                     float* __restrict__ scores) {
  int row = blockIdx.x * 256 + threadIdx.x;
  if (row >= NROWS) return;
  float d2 = fnorm[row] + ord2f(minu[row]);
  scores[row] = sqrtf(fmaxf(d2, 0.f));
}

__global__ __launch_bounds__(256) void image_max_kernel(const float* __restrict__ scores,
                                                        float* __restrict__ out) {
  __shared__ float red[4];
  const int b = blockIdx.x;
  float m = -INFINITY;
  for (int n = threadIdx.x; n < N1; n += 256) m = fmaxf(m, scores[b * N1 + n]);
#pragma unroll
  for (int off = 32; off; off >>= 1) m = fmaxf(m, __shfl_down(m, off, 64));
  if ((threadIdx.x & 63) == 0) red[threadIdx.x >> 6] = m;
  __syncthreads();
  if (threadIdx.x == 0) out[b] = fmaxf(fmaxf(red[0], red[1]), fmaxf(red[2], red[3]));
}

__global__ __launch_bounds__(256) void upsample_kernel(const float* __restrict__ scores,
                                                       float* __restrict__ out) {
  int o = blockIdx.x * 256 + threadIdx.x;
  if (o >= BQ * OUTHW) return;
  int b = o / OUTHW, rem = o % OUTHW;
  int oy = rem / 224, ox = rem % 224;
  float sy = ((float)oy + 0.5f) * 0.125f - 0.5f;
  sy = fminf(fmaxf(sy, 0.f), 27.f);
  int y0 = (int)sy, y1 = min(y0 + 1, 27);
  float wy = sy - (float)y0;
  float sx = ((float)ox + 0.5f) * 0.125f - 0.5f;
  sx = fminf(fmaxf(sx, 0.f), 27.f);
  int x0 = (int)sx, x1 = min(x0 + 1, 27);
  float wx = sx - (float)x0;
  const float* s = scores + b * N1;
  float v0 = s[y0 * 28 + x0] * (1.f - wy) + s[y1 * 28 + x0] * wy;
  float v1 = s[y0 * 28 + x1] * (1.f - wy) + s[y1 * 28 + x1] * wy;
  out[BQ + o] = v0 * (1.f - wx) + v1 * wx;
}

extern "C" void kernel_launch(void* const* d_in, const int* in_sizes, int n_in,
                              void* d_out, int out_size, void* d_ws, size_t ws_size,
                              hipStream_t stream) {
  const float* feat1 = (const float*)d_in[0];
  const float* feat2 = (const float*)d_in[1];
  const float* memory = (const float*)d_in[2];
  float* out = (float*)d_out;

  char* ws = (char*)d_ws;
  size_t off = 0;
  auto wsalloc = [&](size_t bytes) {
    void* p = ws + off;
    off += (bytes + 255) & ~(size_t)255;
    return p;
  };

  u16* At = (u16*)wsalloc((size_t)NTA * NKB * KTE * 2);
  u16* Bt = (u16*)wsalloc((size_t)NTB * NKB * KTE * 2);
  float* mnorm = (float*)wsalloc((size_t)MEMN * 4);
  float* fnorm = (float*)wsalloc((size_t)NROWS * 4);
  unsigned int* minu = (unsigned int*)wsalloc((size_t)NROWSP * 4);
  float* scores = (float*)wsalloc((size_t)NROWS * 4);
  // H2all aliases Bt: stream order guarantees feat_b_stage1/2 finish before memconv
  // overwrites Bt (3.2 MB << Bt's 41 MB).
  float* H2all = (float*)Bt;

  feat_a_bf<<<(BQ * N1 * C1N) / 256, 256, 0, stream>>>(feat1, At);
  feat_b_stage1<<<BQ * M2, 256, 0, stream>>>(feat2, H2all);
  feat_b_stage2<<<BQ * N1, 256, 0, stream>>>(H2all, At);
  memconv<<<(NTB * NKB * 1024) / 256, 256, 0, stream>>>(memory, Bt);
  fnorm_bf<<<NROWS / 4, 256, 0, stream>>>(At, fnorm);
  mnorm_kernel<<<MEMN, 256, 0, stream>>>(memory, mnorm);
  hipMemsetAsync(minu, 0xFF, (size_t)NROWSP * 4, stream);

  dist_min_mfma<<<NWG, 512, 0, stream>>>(At, Bt, mnorm, minu);

  scores_kernel<<<(NROWS + 255) / 256, 256, 0, stream>>>(fnorm, minu, scores);
  image_max_kernel<<<BQ, 256, 0, stream>>>(scores, out);
  upsample_kernel<<<(BQ * OUTHW + 255) / 256, 256, 0, stream>>>(scores, out);
}

// Round 12
// 364.703 us; speedup vs baseline: 7.4855x; 7.4855x over previous
//
#include <hip/hip_runtime.h>
#include <hip/hip_bf16.h>
#include <math.h>

// Problem constants
#define BQ 8
#define C1N 512
#define N1 784          // 28*28
#define C2N 1024
#define M2 196          // 14*14
#define NROWS 6272      // 8*784 = 49*128
#define MEMN 20000
#define MEMNP 20096     // 157*128
#define DIMK 1024
#define NKB 32          // K blocks of 32
#define KTB 4096        // bytes per K-block per 128-row tile (4*128*8 fp8)
#define OUTHW 50176     // 224*224
#define NTILEA 49
#define NTILEB 157
#define NWG (NTILEB * NTILEA)   // 7693

typedef unsigned char u8;
typedef long long i64v;

typedef __attribute__((ext_vector_type(4))) float f32x4;

// ---- order-preserving float <-> uint for atomicMin ----
static __device__ __forceinline__ unsigned int f2ord(float f) {
  unsigned int b = __float_as_uint(f);
  return (b & 0x80000000u) ? ~b : (b | 0x80000000u);
}
static __device__ __forceinline__ float ord2f(unsigned int u) {
  unsigned int b = (u & 0x80000000u) ? (u ^ 0x80000000u) : ~u;
  return __uint_as_float(b);
}

// ---- fp8 e4m3 (OCP) pack/unpack via HW converts ----
static __device__ __forceinline__ int pack4_fp8(float a, float b, float c, float d) {
  int lo = __builtin_amdgcn_cvt_pk_fp8_f32(a, b, 0, false);
  return __builtin_amdgcn_cvt_pk_fp8_f32(c, d, lo, true);
}
// sum of squares of the 4 fp8 lanes of w (sel must be literal constants)
static __device__ __forceinline__ float sumsq4_fp8(int w) {
  float f0 = __builtin_amdgcn_cvt_f32_fp8(w, 0);
  float f1 = __builtin_amdgcn_cvt_f32_fp8(w, 1);
  float f2 = __builtin_amdgcn_cvt_f32_fp8(w, 2);
  float f3 = __builtin_amdgcn_cvt_f32_fp8(w, 3);
  return f0 * f0 + f1 * f1 + f2 * f2 + f3 * f3;
}

// ---- async global->LDS (16B per lane; LDS dest = wave-uniform base + lane*16) ----
static __device__ __forceinline__ void gload16(const void* g, void* l) {
  __builtin_amdgcn_global_load_lds((const __attribute__((address_space(1))) void*)g,
                                   (__attribute__((address_space(3))) void*)l, 16, 0, 0);
}

// ---- tiled (k-major) fp8 byte index, 128-row tiles ----
// layout: [tile][kb=32][c=4][row=128][e=8] bytes; element (grow=tile*128+row, k=kb*32+c*8+e)
static __device__ __forceinline__ size_t tiled_idx(int grow, int k) {
  int tile = grow >> 7, row = grow & 127;
  int kb = k >> 5, c = (k >> 3) & 3, e = k & 7;
  return (((size_t)(tile * NKB + kb) * 4 + c) * 128 + row) * 8 + e;
}

// ---- scrambled patchify flat-index decode ----
// Reference's patchify flattens per-batch in (kj, w, c, ki, h) row-major order:
//   L = (((kj*W + w)*C + c)*3 + ki)*H + h ; value = x[b, c, h+ki-1, w+kj-1] (0 if OOB)
static __device__ __forceinline__ float f1val(const float* __restrict__ x, int b, unsigned L) {
  unsigned h = L % 28u; unsigned t = L / 28u;
  unsigned ki = t % 3u; t /= 3u;
  unsigned c = t % 512u; t /= 512u;
  unsigned w = t % 28u; unsigned kj = t / 28u;
  unsigned y = h + ki - 1u;   // wraps to huge if -1
  unsigned xx = w + kj - 1u;
  if (y >= 28u || xx >= 28u) return 0.f;
  return x[(((size_t)b * 512u + c) * 28u + y) * 28u + xx];
}
static __device__ __forceinline__ float f2val(const float* __restrict__ x, int b, unsigned L) {
  unsigned h = L % 14u; unsigned t = L / 14u;
  unsigned ki = t % 3u; t /= 3u;
  unsigned c = t % 1024u; t /= 1024u;
  unsigned w = t % 14u; unsigned kj = t / 14u;
  unsigned y = h + ki - 1u;
  unsigned xx = w + kj - 1u;
  if (y >= 14u || xx >= 14u) return 0.f;
  return x[(((size_t)b * 1024u + c) * 14u + y) * 14u + xx];
}

// feats[b,n,j<512] = (sum_{u=0..8} F1[9*(512n+j)+u] + F1[...+4]) / 10  -> fp8 tiled
// thread handles 8 consecutive j (one e-run); n fastest across threads -> 8B coalesced
__global__ __launch_bounds__(256) void feat_a_fp8(const float* __restrict__ feat1,
                                                  u8* __restrict__ At) {
  int id = blockIdx.x * 256 + threadIdx.x;
  if (id >= BQ * 64 * N1) return;
  int n = id % N1; int t = id / N1;
  int jc = t % 64; int b = t / 64;
  float v[8];
#pragma unroll
  for (int e = 0; e < 8; ++e) {
    int j = jc * 8 + e;
    unsigned L0 = 9u * (unsigned)(512 * n + j);
    float s = 0.f;
#pragma unroll
    for (int u = 0; u < 9; ++u) s += f1val(feat1, b, L0 + u);
    s += f1val(feat1, b, L0 + 4u);
    v[e] = s * 0.1f;
  }
  int w0 = pack4_fp8(v[0], v[1], v[2], v[3]);
  int w1 = pack4_fp8(v[4], v[5], v[6], v[7]);
  *(int2*)&At[tiled_idx(b * N1 + n, jc * 8)] = make_int2(w0, w1);
}

// H2all[b][n2][i] = (1/18) sum_{u<18} F2[18*(512*n2+i)+u]
__global__ __launch_bounds__(256) void feat_b_stage1(const float* __restrict__ feat2,
                                                     float* __restrict__ H2all) {
  int b = blockIdx.x / M2;
  int n2 = blockIdx.x % M2;
  for (int i = threadIdx.x; i < 512; i += 256) {
    unsigned L0 = 18u * (unsigned)(512 * n2 + i);
    float s = 0.f;
#pragma unroll
    for (int u = 0; u < 18; ++u) s += f2val(feat2, b, L0 + u);
    H2all[((size_t)b * M2 + n2) * 512 + i] = s * (1.0f / 18.0f);
  }
}

// bilinear 14x14 -> 28x28 over the n2 grid, write feats[b,n,512+i] -> fp8 tiled
__global__ __launch_bounds__(256) void feat_b_stage2_fp8(const float* __restrict__ H2all,
                                                         u8* __restrict__ At) {
  int id = blockIdx.x * 256 + threadIdx.x;
  if (id >= BQ * 64 * N1) return;
  int n = id % N1; int t = id / N1;
  int ic = t % 64; int b = t / 64;
  int y = n / 28, x = n % 28;
  float sy = 0.5f * (float)y - 0.25f;
  sy = fminf(fmaxf(sy, 0.f), 13.f);
  int y0 = (int)sy, y1 = min(y0 + 1, 13);
  float wy = sy - (float)y0;
  float sx = 0.5f * (float)x - 0.25f;
  sx = fminf(fmaxf(sx, 0.f), 13.f);
  int x0 = (int)sx, x1 = min(x0 + 1, 13);
  float wx = sx - (float)x0;
  float w00 = (1.f - wy) * (1.f - wx), w10 = wy * (1.f - wx);
  float w01 = (1.f - wy) * wx, w11 = wy * wx;
  const float* h00 = H2all + ((size_t)b * M2 + y0 * 14 + x0) * 512 + ic * 8;
  const float* h10 = H2all + ((size_t)b * M2 + y1 * 14 + x0) * 512 + ic * 8;
  const float* h01 = H2all + ((size_t)b * M2 + y0 * 14 + x1) * 512 + ic * 8;
  const float* h11 = H2all + ((size_t)b * M2 + y1 * 14 + x1) * 512 + ic * 8;
  float v[8];
#pragma unroll
  for (int e = 0; e < 8; ++e)
    v[e] = w00 * h00[e] + w10 * h10[e] + w01 * h01[e] + w11 * h11[e];
  int w0 = pack4_fp8(v[0], v[1], v[2], v[3]);
  int w1 = pack4_fp8(v[4], v[5], v[6], v[7]);
  *(int2*)&At[tiled_idx(b * N1 + n, 512 + ic * 8)] = make_int2(w0, w1);
}

// memory fp32 -> fp8 tiled; rows [MEMN, MEMNP) = 0. One 8-elem unit per thread,
// dst linear in gid -> coalesced 8B writes.
__global__ __launch_bounds__(256) void memconv_fp8(const float* __restrict__ mem,
                                                   u8* __restrict__ Bt) {
  int gid = blockIdx.x * 256 + threadIdx.x;
  if (gid >= NTILEB * NKB * 512) return;
  int tile = gid >> 14;            // 32*512 units per tile
  int within = gid & 16383;
  int kb = within >> 9;
  int u = within & 511;
  int c = u >> 7, row = u & 127;
  int n = tile * 128 + row;
  int k0 = kb * 32 + c * 8;
  int w0 = 0, w1 = 0;
  if (n < MEMN) {
    const float* src = mem + (size_t)n * DIMK + k0;
    float4 a = *(const float4*)src;
    float4 b = *(const float4*)(src + 4);
    w0 = pack4_fp8(a.x, a.y, a.z, a.w);
    w1 = pack4_fp8(b.x, b.y, b.z, b.w);
  }
  *(int2*)&Bt[(size_t)gid * 8] = make_int2(w0, w1);
}

// fnorm from fp8 tiled feats (quantized values for consistency): 1 wave per row
__global__ __launch_bounds__(256) void fnorm_fp8(const u8* __restrict__ At,
                                                 float* __restrict__ fnorm) {
  int row = blockIdx.x * 4 + (threadIdx.x >> 6);
  int lane = threadIdx.x & 63;
  float s = 0.f;
#pragma unroll
  for (int qq = 0; qq < 2; ++qq) {
    int kc = lane * 2 + qq;   // chunk 0..127 -> k = kc*8
    int2 d = *(const int2*)&At[tiled_idx(row, kc * 8)];
    s += sumsq4_fp8(d.x);
    s += sumsq4_fp8(d.y);
  }
#pragma unroll
  for (int off = 32; off; off >>= 1) s += __shfl_down(s, off, 64);
  if (lane == 0) fnorm[row] = s;
}

// mnorm from fp8-quantized memory values (consistency with GEMM operand)
__global__ __launch_bounds__(256) void mnorm_fp8(const float* __restrict__ memory,
                                                 float* __restrict__ mnorm) {
  __shared__ float red[4];
  const int row = blockIdx.x;
  const float4 v = *(const float4*)&memory[(size_t)row * DIMK + threadIdx.x * 4];
  int p0 = __builtin_amdgcn_cvt_pk_fp8_f32(v.x, v.y, 0, false);
  int p1 = __builtin_amdgcn_cvt_pk_fp8_f32(v.z, v.w, 0, false);
  float q0 = __builtin_amdgcn_cvt_f32_fp8(p0, 0);
  float q1 = __builtin_amdgcn_cvt_f32_fp8(p0, 1);
  float q2 = __builtin_amdgcn_cvt_f32_fp8(p1, 0);
  float q3 = __builtin_amdgcn_cvt_f32_fp8(p1, 1);
  float s = q0 * q0 + q1 * q1 + q2 * q2 + q3 * q3;
#pragma unroll
  for (int off = 32; off; off >>= 1) s += __shfl_down(s, off, 64);
  if ((threadIdx.x & 63) == 0) red[threadIdx.x >> 6] = s;
  __syncthreads();
  if (threadIdx.x == 0) mnorm[row] = red[0] + red[1] + red[2] + red[3];
}

// ---- fp8 MFMA distance GEMM + row-min ----
// 128x128 tile, BK=32, 4 waves (2x2), 3-buffer LDS pipeline (24 KB), static unroll,
// counted vmcnt(2) (2 gloads/stage), setprio cluster. 4 blocks/CU via (256,4).
__global__ __launch_bounds__(256, 4) void dist_min_mfma(const u8* __restrict__ At,
                                                        const u8* __restrict__ Bt,
                                                        const float* __restrict__ mnorm,
                                                        unsigned int* __restrict__ minu) {
  __shared__ __align__(16) u8 LAs[3][4096];
  __shared__ __align__(16) u8 LBs[3][4096];
  const int t = threadIdx.x;
  const int wave = t >> 6, lane = t & 63;

  // bijective XCD chunking (m204): q=961, r=5
  int lid = blockIdx.x;
  const int q = NWG / 8, r = NWG % 8;
  int xcd = lid & 7, pos = lid >> 3;
  int wgid = (xcd < r ? xcd * (q + 1) : r * (q + 1) + (xcd - r) * q) + pos;
  // supertile: 7 row-tiles per group (49 = 7*7), rows fastest within a column
  int g = wgid / (NTILEB * 7), rem = wgid % (NTILEB * 7);
  int bx = rem / 7;            // col tile 0..156
  int by = g * 7 + rem % 7;    // row tile 0..48
  const int row0 = by * 128, col0 = bx * 128;

  f32x4 acc[4][4];
#pragma unroll
  for (int i = 0; i < 4; ++i)
#pragma unroll
    for (int j = 0; j < 4; ++j) acc[i][j] = (f32x4){0.f, 0.f, 0.f, 0.f};

  const int wr = (wave >> 1) * 64, wc = (wave & 1) * 64;
  const int frow = lane & 15, fc = lane >> 4;
  const int aoff = fc * 1024 + (wr + frow) * 8;   // + mi*128 bytes
  const int boff = fc * 1024 + (wc + frow) * 8;   // + ni*128 bytes
  const int soff = wave * 1024 + lane * 16;       // staging byte offset in 4096-B tile

  const u8* aG = At + (size_t)by * (NKB * KTB) + soff;
  const u8* bG = Bt + (size_t)bx * (NKB * KTB) + soff;

  // stage one K-tile (A 4KB + B 4KB) into static slot; advance pointers
#define STAGE(buf)                            \
  do {                                        \
    gload16(aG, &LAs[buf][wave * 1024]);      \
    gload16(bG, &LBs[buf][wave * 1024]);      \
    aG += KTB; bG += KTB;                     \
  } while (0)

  // compute one K-tile from static slot
#define COMPUTE(buf)                                                                         \
  do {                                                                                       \
    i64v a[4], b[4];                                                                         \
    _Pragma("unroll") for (int mi = 0; mi < 4; ++mi)                                         \
        a[mi] = *(const i64v*)&LAs[buf][aoff + mi * 128];                                    \
    _Pragma("unroll") for (int ni = 0; ni < 4; ++ni)                                         \
        b[ni] = *(const i64v*)&LBs[buf][boff + ni * 128];                                    \
    __builtin_amdgcn_s_setprio(1);                                                           \
    _Pragma("unroll") for (int mi = 0; mi < 4; ++mi)                                         \
      _Pragma("unroll") for (int ni = 0; ni < 4; ++ni)                                       \
          acc[mi][ni] = __builtin_amdgcn_mfma_f32_16x16x32_fp8_fp8(a[mi], b[ni],             \
                                                                   acc[mi][ni], 0, 0, 0);    \
    __builtin_amdgcn_s_setprio(0);                                                           \
  } while (0)

#define WAITBAR(n)                                        \
  do {                                                    \
    asm volatile("s_waitcnt vmcnt(" #n ")" ::: "memory"); \
    __builtin_amdgcn_s_barrier();                         \
  } while (0)

  STAGE(0);
  STAGE(1);
  WAITBAR(2);   // tile 0 landed, tile 1 in flight

  // 32 K-tiles: 10 iterations x 3 static slots = tiles 0..29, then 30, 31
#pragma unroll 1
  for (int i = 0; i < 10; ++i) {
    STAGE(2); COMPUTE(0); WAITBAR(2);
    STAGE(0); COMPUTE(1); WAITBAR(2);
    STAGE(1); COMPUTE(2); WAITBAR(2);
  }
  COMPUTE(0);    // tile 30
  WAITBAR(0);    // drain tile 31
  COMPUTE(1);    // tile 31
#undef STAGE
#undef COMPUTE
#undef WAITBAR

  // epilogue: v = mnorm[col] - 2*dot ; row-min across the 16-lane group
  float cmn[4];
#pragma unroll
  for (int ni = 0; ni < 4; ++ni) {
    int gn = col0 + wc + ni * 16 + frow;
    cmn[ni] = (gn < MEMN) ? mnorm[gn] : INFINITY;
  }
#pragma unroll
  for (int mi = 0; mi < 4; ++mi) {
#pragma unroll
    for (int rr = 0; rr < 4; ++rr) {
      float v = INFINITY;
#pragma unroll
      for (int ni = 0; ni < 4; ++ni)
        v = fminf(v, fmaf(-2.f, acc[mi][ni][rr], cmn[ni]));
#pragma unroll
      for (int off = 1; off < 16; off <<= 1)
        v = fminf(v, __shfl_xor(v, off, 64));
      if (frow == 0) {
        int grow = row0 + wr + mi * 16 + (lane >> 4) * 4 + rr;
        atomicMin(&minu[grow], f2ord(v));
      }
    }
  }
}

// ================= epilogue kernels =================

__global__ __launch_bounds__(256) void scores_kernel(const float* __restrict__ fnorm,
                                                     const unsigned int* __restrict__ minu,
                                                     float* __restrict__ scores) {
  int row = blockIdx.x * 256 + threadIdx.x;
  if (row >= NROWS) return;
  float d2 = fnorm[row] + ord2f(minu[row]);
  scores[row] = sqrtf(fmaxf(d2, 0.f));
}

__global__ __launch_bounds__(256) void image_max_kernel(const float* __restrict__ scores,
                                                        float* __restrict__ out) {
  __shared__ float red[4];
  const int b = blockIdx.x;
  float m = -INFINITY;
  for (int n = threadIdx.x; n < N1; n += 256) m = fmaxf(m, scores[b * N1 + n]);
#pragma unroll
  for (int off = 32; off; off >>= 1) m = fmaxf(m, __shfl_down(m, off, 64));
  if ((threadIdx.x & 63) == 0) red[threadIdx.x >> 6] = m;
  __syncthreads();
  if (threadIdx.x == 0) out[b] = fmaxf(fmaxf(red[0], red[1]), fmaxf(red[2], red[3]));
}

__global__ __launch_bounds__(256) void upsample_kernel(const float* __restrict__ scores,
                                                       float* __restrict__ out) {
  int o = blockIdx.x * 256 + threadIdx.x;
  if (o >= BQ * OUTHW) return;
  int b = o / OUTHW, rem = o % OUTHW;
  int oy = rem / 224, ox = rem % 224;
  float sy = ((float)oy + 0.5f) * 0.125f - 0.5f;
  sy = fminf(fmaxf(sy, 0.f), 27.f);
  int y0 = (int)sy, y1 = min(y0 + 1, 27);
  float wy = sy - (float)y0;
  float sx = ((float)ox + 0.5f) * 0.125f - 0.5f;
  sx = fminf(fmaxf(sx, 0.f), 27.f);
  int x0 = (int)sx, x1 = min(x0 + 1, 27);
  float wx = sx - (float)x0;
  const float* s = scores + b * N1;
  float v0 = s[y0 * 28 + x0] * (1.f - wy) + s[y1 * 28 + x0] * wy;
  float v1 = s[y0 * 28 + x1] * (1.f - wy) + s[y1 * 28 + x1] * wy;
  out[BQ + o] = v0 * (1.f - wx) + v1 * wx;
}

extern "C" void kernel_launch(void* const* d_in, const int* in_sizes, int n_in,
                              void* d_out, int out_size, void* d_ws, size_t ws_size,
                              hipStream_t stream) {
  const float* feat1 = (const float*)d_in[0];
  const float* feat2 = (const float*)d_in[1];
  const float* memory = (const float*)d_in[2];
  float* out = (float*)d_out;

  char* ws = (char*)d_ws;
  size_t off = 0;
  auto wsalloc = [&](size_t bytes) {
    void* p = ws + off;
    off += (bytes + 255) & ~(size_t)255;
    return p;
  };

  u8* At = (u8*)wsalloc((size_t)NTILEA * NKB * KTB);   // 6.4 MB
  u8* Bt = (u8*)wsalloc((size_t)NTILEB * NKB * KTB);   // 20.6 MB
  float* mnorm = (float*)wsalloc((size_t)MEMN * 4);
  float* fnorm = (float*)wsalloc((size_t)NROWS * 4);
  unsigned int* minu = (unsigned int*)wsalloc((size_t)NROWS * 4);
  float* scores = (float*)wsalloc((size_t)NROWS * 4);
  // H2all aliases Bt: stream order guarantees feat_b_stage1/2 finish before memconv
  // overwrites Bt (3.2 MB << Bt's 20.6 MB).
  float* H2all = (float*)Bt;

  feat_a_fp8<<<(BQ * 64 * N1) / 256, 256, 0, stream>>>(feat1, At);
  feat_b_stage1<<<BQ * M2, 256, 0, stream>>>(feat2, H2all);
  feat_b_stage2_fp8<<<(BQ * 64 * N1) / 256, 256, 0, stream>>>(H2all, At);
  memconv_fp8<<<(NTILEB * NKB * 512) / 256, 256, 0, stream>>>(memory, Bt);
  fnorm_fp8<<<NROWS / 4, 256, 0, stream>>>(At, fnorm);
  mnorm_fp8<<<MEMN, 256, 0, stream>>>(memory, mnorm);
  hipMemsetAsync(minu, 0xFF, (size_t)NROWS * 4, stream);

  dist_min_mfma<<<NWG, 256, 0, stream>>>(At, Bt, mnorm, minu);

  scores_kernel<<<(NROWS + 255) / 256, 256, 0, stream>>>(fnorm, minu, scores);
  image_max_kernel<<<BQ, 256, 0, stream>>>(scores, out);
  upsample_kernel<<<(BQ * OUTHW + 255) / 256, 256, 0, stream>>>(scores, out);
}

// Round 13
// 346.304 us; speedup vs baseline: 7.8833x; 1.0531x over previous
//
#include <hip/hip_runtime.h>
#include <hip/hip_bf16.h>
#include <math.h>

// Problem constants
#define BQ 8
#define C1N 512
#define N1 784          // 28*28
#define C2N 1024
#define M2 196          // 14*14
#define NROWS 6272      // 8*784 = 49*128
#define MEMN 20000
#define MEMNP 20096     // 157*128
#define DIMK 1024
#define NSLAB 8         // K slabs of 128
#define SLB 16384       // bytes per K-slab per 128-row tile (128*128 fp8)
#define OUTHW 50176     // 224*224
#define NTILEA 49
#define NTILEB 157
#define NWG (NTILEB * NTILEA)   // 7693

typedef unsigned char u8;
typedef __attribute__((ext_vector_type(8))) int i32x8;
typedef __attribute__((ext_vector_type(4))) float f32x4;

// ---- order-preserving float <-> uint for atomicMin ----
static __device__ __forceinline__ unsigned int f2ord(float f) {
  unsigned int b = __float_as_uint(f);
  return (b & 0x80000000u) ? ~b : (b | 0x80000000u);
}
static __device__ __forceinline__ float ord2f(unsigned int u) {
  unsigned int b = (u & 0x80000000u) ? (u ^ 0x80000000u) : ~u;
  return __uint_as_float(b);
}

// ---- fp8 e4m3 (OCP) pack/unpack via HW converts ----
static __device__ __forceinline__ int pack4_fp8(float a, float b, float c, float d) {
  int lo = __builtin_amdgcn_cvt_pk_fp8_f32(a, b, 0, false);
  return __builtin_amdgcn_cvt_pk_fp8_f32(c, d, lo, true);
}
static __device__ __forceinline__ float sumsq4_fp8(int w) {
  float f0 = __builtin_amdgcn_cvt_f32_fp8(w, 0);
  float f1 = __builtin_amdgcn_cvt_f32_fp8(w, 1);
  float f2 = __builtin_amdgcn_cvt_f32_fp8(w, 2);
  float f3 = __builtin_amdgcn_cvt_f32_fp8(w, 3);
  return f0 * f0 + f1 * f1 + f2 * f2 + f3 * f3;
}

// ---- async global->LDS (16B per lane; LDS dest = wave-uniform base + lane*16) ----
static __device__ __forceinline__ void gload16(const void* g, void* l) {
  __builtin_amdgcn_global_load_lds((const __attribute__((address_space(1))) void*)g,
                                   (__attribute__((address_space(3))) void*)l, 16, 0, 0);
}

// ---- MX-tiled fp8 layout: [tile128][slab=8][1024 swizzled 16B chunks] ----
// logical chunk c = fc*256 + row*2 + h  (fc = k-quarter of 32, h = 16B half)
// physical chunk p = c ^ ((c>>3)&7)  (involution; uniform b128 bank spread)
static __device__ __forceinline__ size_t chunk_addr(int grow, int k) {
  int tile = grow >> 7, row = grow & 127;
  int kb = k >> 7;
  int c = ((k >> 5) & 3) * 256 + row * 2 + ((k >> 4) & 1);
  int p = c ^ ((c >> 3) & 7);
  return ((size_t)(tile * NSLAB + kb) * 1024 + p) * 16;
}

// ---- scrambled patchify flat-index decode ----
// Reference's patchify flattens per-batch in (kj, w, c, ki, h) row-major order:
//   L = (((kj*W + w)*C + c)*3 + ki)*H + h ; value = x[b, c, h+ki-1, w+kj-1] (0 if OOB)
static __device__ __forceinline__ float f1val(const float* __restrict__ x, int b, unsigned L) {
  unsigned h = L % 28u; unsigned t = L / 28u;
  unsigned ki = t % 3u; t /= 3u;
  unsigned c = t % 512u; t /= 512u;
  unsigned w = t % 28u; unsigned kj = t / 28u;
  unsigned y = h + ki - 1u;   // wraps to huge if -1
  unsigned xx = w + kj - 1u;
  if (y >= 28u || xx >= 28u) return 0.f;
  return x[(((size_t)b * 512u + c) * 28u + y) * 28u + xx];
}
static __device__ __forceinline__ float f2val(const float* __restrict__ x, int b, unsigned L) {
  unsigned h = L % 14u; unsigned t = L / 14u;
  unsigned ki = t % 3u; t /= 3u;
  unsigned c = t % 1024u; t /= 1024u;
  unsigned w = t % 14u; unsigned kj = t / 14u;
  unsigned y = h + ki - 1u;
  unsigned xx = w + kj - 1u;
  if (y >= 14u || xx >= 14u) return 0.f;
  return x[(((size_t)b * 1024u + c) * 14u + y) * 14u + xx];
}

// feats[b,n,j<512] = (sum_{u=0..8} F1[9*(512n+j)+u] + F1[...+4]) / 10  -> fp8 MX-tiled
__global__ __launch_bounds__(256) void feat_a_fp8(const float* __restrict__ feat1,
                                                  u8* __restrict__ At) {
  int id = blockIdx.x * 256 + threadIdx.x;
  if (id >= BQ * 64 * N1) return;
  int n = id % N1; int t = id / N1;
  int jc = t % 64; int b = t / 64;
  float v[8];
#pragma unroll
  for (int e = 0; e < 8; ++e) {
    int j = jc * 8 + e;
    unsigned L0 = 9u * (unsigned)(512 * n + j);
    float s = 0.f;
#pragma unroll
    for (int u = 0; u < 9; ++u) s += f1val(feat1, b, L0 + u);
    s += f1val(feat1, b, L0 + 4u);
    v[e] = s * 0.1f;
  }
  int w0 = pack4_fp8(v[0], v[1], v[2], v[3]);
  int w1 = pack4_fp8(v[4], v[5], v[6], v[7]);
  int k0 = jc * 8;
  *(int2*)&At[chunk_addr(b * N1 + n, k0) + (k0 & 15)] = make_int2(w0, w1);
}

// H2all[b][n2][i] = (1/18) sum_{u<18} F2[18*(512*n2+i)+u]
__global__ __launch_bounds__(256) void feat_b_stage1(const float* __restrict__ feat2,
                                                     float* __restrict__ H2all) {
  int b = blockIdx.x / M2;
  int n2 = blockIdx.x % M2;
  for (int i = threadIdx.x; i < 512; i += 256) {
    unsigned L0 = 18u * (unsigned)(512 * n2 + i);
    float s = 0.f;
#pragma unroll
    for (int u = 0; u < 18; ++u) s += f2val(feat2, b, L0 + u);
    H2all[((size_t)b * M2 + n2) * 512 + i] = s * (1.0f / 18.0f);
  }
}

// bilinear 14x14 -> 28x28 over the n2 grid, write feats[b,n,512+i] -> fp8 MX-tiled
__global__ __launch_bounds__(256) void feat_b_stage2_fp8(const float* __restrict__ H2all,
                                                         u8* __restrict__ At) {
  int id = blockIdx.x * 256 + threadIdx.x;
  if (id >= BQ * 64 * N1) return;
  int n = id % N1; int t = id / N1;
  int ic = t % 64; int b = t / 64;
  int y = n / 28, x = n % 28;
  float sy = 0.5f * (float)y - 0.25f;
  sy = fminf(fmaxf(sy, 0.f), 13.f);
  int y0 = (int)sy, y1 = min(y0 + 1, 13);
  float wy = sy - (float)y0;
  float sx = 0.5f * (float)x - 0.25f;
  sx = fminf(fmaxf(sx, 0.f), 13.f);
  int x0 = (int)sx, x1 = min(x0 + 1, 13);
  float wx = sx - (float)x0;
  float w00 = (1.f - wy) * (1.f - wx), w10 = wy * (1.f - wx);
  float w01 = (1.f - wy) * wx, w11 = wy * wx;
  const float* h00 = H2all + ((size_t)b * M2 + y0 * 14 + x0) * 512 + ic * 8;
  const float* h10 = H2all + ((size_t)b * M2 + y1 * 14 + x0) * 512 + ic * 8;
  const float* h01 = H2all + ((size_t)b * M2 + y0 * 14 + x1) * 512 + ic * 8;
  const float* h11 = H2all + ((size_t)b * M2 + y1 * 14 + x1) * 512 + ic * 8;
  float v[8];
#pragma unroll
  for (int e = 0; e < 8; ++e)
    v[e] = w00 * h00[e] + w10 * h10[e] + w01 * h01[e] + w11 * h11[e];
  int w0 = pack4_fp8(v[0], v[1], v[2], v[3]);
  int w1 = pack4_fp8(v[4], v[5], v[6], v[7]);
  int k0 = 512 + ic * 8;
  *(int2*)&At[chunk_addr(b * N1 + n, k0) + (k0 & 15)] = make_int2(w0, w1);
}

// memory fp32 -> fp8 MX-tiled; rows [MEMN, MEMNP) = 0. One 16B chunk per thread,
// dst linear in gid -> coalesced 16B writes.
__global__ __launch_bounds__(256) void memconv_fp8(const float* __restrict__ mem,
                                                   u8* __restrict__ Bt) {
  int gid = blockIdx.x * 256 + threadIdx.x;
  if (gid >= NTILEB * NSLAB * 1024) return;
  int p = gid & 1023;
  int kb = (gid >> 10) & 7;
  int tile = gid >> 13;
  int c = p ^ ((p >> 3) & 7);
  int fc = c >> 8, row = (c >> 1) & 127, h = c & 1;
  int n = tile * 128 + row;
  int k0 = kb * 128 + fc * 32 + h * 16;
  int4 o = make_int4(0, 0, 0, 0);
  if (n < MEMN) {
    const float* src = mem + (size_t)n * DIMK + k0;
    float4 a = *(const float4*)src;
    float4 b = *(const float4*)(src + 4);
    float4 cc = *(const float4*)(src + 8);
    float4 d = *(const float4*)(src + 12);
    o.x = pack4_fp8(a.x, a.y, a.z, a.w);
    o.y = pack4_fp8(b.x, b.y, b.z, b.w);
    o.z = pack4_fp8(cc.x, cc.y, cc.z, cc.w);
    o.w = pack4_fp8(d.x, d.y, d.z, d.w);
  }
  *(int4*)&Bt[(size_t)gid * 16] = o;
}

// fnorm from fp8 tiled feats (quantized values): 1 wave per row, 1 chunk per lane
__global__ __launch_bounds__(256) void fnorm_fp8(const u8* __restrict__ At,
                                                 float* __restrict__ fnorm) {
  int row = blockIdx.x * 4 + (threadIdx.x >> 6);
  int lane = threadIdx.x & 63;
  int4 d = *(const int4*)&At[chunk_addr(row, lane * 16)];
  float s = sumsq4_fp8(d.x) + sumsq4_fp8(d.y) + sumsq4_fp8(d.z) + sumsq4_fp8(d.w);
#pragma unroll
  for (int off = 32; off; off >>= 1) s += __shfl_down(s, off, 64);
  if (lane == 0) fnorm[row] = s;
}

// mnorm from fp8-quantized memory values (consistency with GEMM operand)
__global__ __launch_bounds__(256) void mnorm_fp8(const float* __restrict__ memory,
                                                 float* __restrict__ mnorm) {
  __shared__ float red[4];
  const int row = blockIdx.x;
  const float4 v = *(const float4*)&memory[(size_t)row * DIMK + threadIdx.x * 4];
  int p0 = __builtin_amdgcn_cvt_pk_fp8_f32(v.x, v.y, 0, false);
  int p1 = __builtin_amdgcn_cvt_pk_fp8_f32(v.z, v.w, 0, false);
  float q0 = __builtin_amdgcn_cvt_f32_fp8(p0, 0);
  float q1 = __builtin_amdgcn_cvt_f32_fp8(p0, 1);
  float q2 = __builtin_amdgcn_cvt_f32_fp8(p1, 0);
  float q3 = __builtin_amdgcn_cvt_f32_fp8(p1, 1);
  float s = q0 * q0 + q1 * q1 + q2 * q2 + q3 * q3;
#pragma unroll
  for (int off = 32; off; off >>= 1) s += __shfl_down(s, off, 64);
  if ((threadIdx.x & 63) == 0) red[threadIdx.x >> 6] = s;
  __syncthreads();
  if (threadIdx.x == 0) mnorm[row] = red[0] + red[1] + red[2] + red[3];
}

// ---- MX-fp8 MFMA distance GEMM + row-min ----
// 128x128 tile, K-slab 128 (8 slabs), 4 waves (2x2), 2 LDS slots (64 KB -> 2 blocks/CU).
// Per slab: STAGE(next slab -> S^1, 8 gloads) ; 16 ds_read_b128 + 16 K=128 MFMA
// (setprio) ; vmcnt(0) (loads had the whole MFMA window in flight) ; barrier.
// Scales are unit (E8M0 0x7F = 2^0) -> plain fp8 GEMM at the 2x MX rate.
__global__ __launch_bounds__(256, 2) void dist_min_mfma(const u8* __restrict__ At,
                                                        const u8* __restrict__ Bt,
                                                        const float* __restrict__ mnorm,
                                                        unsigned int* __restrict__ minu) {
  __shared__ __align__(16) u8 LAs[2][SLB];
  __shared__ __align__(16) u8 LBs[2][SLB];
  const int t = threadIdx.x;
  const int wave = t >> 6, lane = t & 63;

  // bijective XCD chunking (m204): q=961, r=5
  int lid = blockIdx.x;
  const int q = NWG / 8, r = NWG % 8;
  int xcd = lid & 7, pos = lid >> 3;
  int wgid = (xcd < r ? xcd * (q + 1) : r * (q + 1) + (xcd - r) * q) + pos;
  // supertile: 7 row-tiles per group (49 = 7*7), rows fastest within a column
  int g = wgid / (NTILEB * 7), rem = wgid % (NTILEB * 7);
  int bx = rem / 7;            // col tile 0..156
  int by = g * 7 + rem % 7;    // row tile 0..48
  const int row0 = by * 128, col0 = bx * 128;

  f32x4 acc[4][4];
#pragma unroll
  for (int i = 0; i < 4; ++i)
#pragma unroll
    for (int j = 0; j < 4; ++j) acc[i][j] = (f32x4){0.f, 0.f, 0.f, 0.f};

  const int wr = (wave >> 1) * 64, wc = (wave & 1) * 64;
  const int frow = lane & 15, fc = lane >> 4;

  // per-lane swizzled chunk byte-offsets within a slab (constant across slabs)
  int aCh[4][2], bCh[4][2];
#pragma unroll
  for (int mi = 0; mi < 4; ++mi) {
    int R = wr + mi * 16 + frow;
    int C = wc + mi * 16 + frow;
#pragma unroll
    for (int h = 0; h < 2; ++h) {
      int ca = fc * 256 + R * 2 + h;
      aCh[mi][h] = (ca ^ ((ca >> 3) & 7)) * 16;
      int cb = fc * 256 + C * 2 + h;
      bCh[mi][h] = (cb ^ ((cb >> 3) & 7)) * 16;
    }
  }

  const int sdst = wave * 1024;   // wave-uniform LDS dst base per staging round
  const u8* aG = At + (size_t)by * (NSLAB * SLB) + wave * 1024 + lane * 16;
  const u8* bG = Bt + (size_t)bx * (NSLAB * SLB) + wave * 1024 + lane * 16;

#define STAGE(S)                                          \
  do {                                                    \
    _Pragma("unroll") for (int rr = 0; rr < 4; ++rr)      \
        gload16(aG + rr * 4096, &LAs[S][rr * 4096 + sdst]); \
    _Pragma("unroll") for (int rr = 0; rr < 4; ++rr)      \
        gload16(bG + rr * 4096, &LBs[S][rr * 4096 + sdst]); \
    aG += SLB; bG += SLB;                                 \
  } while (0)

#define COMPUTE(S)                                                                           \
  do {                                                                                       \
    i32x8 a[4], b[4];                                                                        \
    _Pragma("unroll") for (int mi = 0; mi < 4; ++mi) {                                       \
      int4 lo = *(const int4*)&LAs[S][aCh[mi][0]];                                           \
      int4 hi = *(const int4*)&LAs[S][aCh[mi][1]];                                           \
      a[mi] = (i32x8){lo.x, lo.y, lo.z, lo.w, hi.x, hi.y, hi.z, hi.w};                       \
    }                                                                                        \
    _Pragma("unroll") for (int ni = 0; ni < 4; ++ni) {                                       \
      int4 lo = *(const int4*)&LBs[S][bCh[ni][0]];                                           \
      int4 hi = *(const int4*)&LBs[S][bCh[ni][1]];                                           \
      b[ni] = (i32x8){lo.x, lo.y, lo.z, lo.w, hi.x, hi.y, hi.z, hi.w};                       \
    }                                                                                        \
    __builtin_amdgcn_s_setprio(1);                                                           \
    _Pragma("unroll") for (int mi = 0; mi < 4; ++mi)                                         \
      _Pragma("unroll") for (int ni = 0; ni < 4; ++ni)                                       \
          acc[mi][ni] = __builtin_amdgcn_mfma_scale_f32_16x16x128_f8f6f4(                    \
              a[mi], b[ni], acc[mi][ni], 0, 0, 0, 0x7F7F7F7F, 0, 0x7F7F7F7F);                \
    __builtin_amdgcn_s_setprio(0);                                                           \
  } while (0)

#define VMW0 asm volatile("s_waitcnt vmcnt(0)" ::: "memory")
#define SBAR __builtin_amdgcn_s_barrier()

  // prologue: slab 0 -> slot 0
  STAGE(0);
  VMW0;
  SBAR;

  // 8 slabs: slab t in slot t&1; stage t+1 during t
#pragma unroll 1
  for (int i = 0; i < 3; ++i) {
    STAGE(1); COMPUTE(0); VMW0; SBAR;   // slabs 0,2,4
    STAGE(0); COMPUTE(1); VMW0; SBAR;   // slabs 1,3,5
  }
  STAGE(1); COMPUTE(0); VMW0; SBAR;     // slab 6, stages slab 7
  COMPUTE(1);                            // slab 7
#undef STAGE
#undef COMPUTE
#undef VMW0
#undef SBAR

  // epilogue: v = mnorm[col] - 2*dot ; row-min across the 16-lane group
  float cmn[4];
#pragma unroll
  for (int ni = 0; ni < 4; ++ni) {
    int gn = col0 + wc + ni * 16 + frow;
    cmn[ni] = (gn < MEMN) ? mnorm[gn] : INFINITY;
  }
#pragma unroll
  for (int mi = 0; mi < 4; ++mi) {
#pragma unroll
    for (int rr = 0; rr < 4; ++rr) {
      float v = INFINITY;
#pragma unroll
      for (int ni = 0; ni < 4; ++ni)
        v = fminf(v, fmaf(-2.f, acc[mi][ni][rr], cmn[ni]));
#pragma unroll
      for (int off = 1; off < 16; off <<= 1)
        v = fminf(v, __shfl_xor(v, off, 64));
      if (frow == 0) {
        int grow = row0 + wr + mi * 16 + (lane >> 4) * 4 + rr;
        atomicMin(&minu[grow], f2ord(v));
      }
    }
  }
}

// ================= epilogue kernels =================

__global__ __launch_bounds__(256) void scores_kernel(const float* __restrict__ fnorm,
                                                     const unsigned int* __restrict__ minu,
                                                     float* __restrict__ scores) {
  int row = blockIdx.x * 256 + threadIdx.x;
  if (row >= NROWS) return;
  float d2 = fnorm[row] + ord2f(minu[row]);
  scores[row] = sqrtf(fmaxf(d2, 0.f));
}

__global__ __launch_bounds__(256) void image_max_kernel(const float* __restrict__ scores,
                                                        float* __restrict__ out) {
  __shared__ float red[4];
  const int b = blockIdx.x;
  float m = -INFINITY;
  for (int n = threadIdx.x; n < N1; n += 256) m = fmaxf(m, scores[b * N1 + n]);
#pragma unroll
  for (int off = 32; off; off >>= 1) m = fmaxf(m, __shfl_down(m, off, 64));
  if ((threadIdx.x & 63) == 0) red[threadIdx.x >> 6] = m;
  __syncthreads();
  if (threadIdx.x == 0) out[b] = fmaxf(fmaxf(red[0], red[1]), fmaxf(red[2], red[3]));
}

__global__ __launch_bounds__(256) void upsample_kernel(const float* __restrict__ scores,
                                                       float* __restrict__ out) {
  int o = blockIdx.x * 256 + threadIdx.x;
  if (o >= BQ * OUTHW) return;
  int b = o / OUTHW, rem = o % OUTHW;
  int oy = rem / 224, ox = rem % 224;
  float sy = ((float)oy + 0.5f) * 0.125f - 0.5f;
  sy = fminf(fmaxf(sy, 0.f), 27.f);
  int y0 = (int)sy, y1 = min(y0 + 1, 27);
  float wy = sy - (float)y0;
  float sx = ((float)ox + 0.5f) * 0.125f - 0.5f;
  sx = fminf(fmaxf(sx, 0.f), 27.f);
  int x0 = (int)sx, x1 = min(x0 + 1, 27);
  float wx = sx - (float)x0;
  const float* s = scores + b * N1;
  float v0 = s[y0 * 28 + x0] * (1.f - wy) + s[y1 * 28 + x0] * wy;
  float v1 = s[y0 * 28 + x1] * (1.f - wy) + s[y1 * 28 + x1] * wy;
  out[BQ + o] = v0 * (1.f - wx) + v1 * wx;
}

extern "C" void kernel_launch(void* const* d_in, const int* in_sizes, int n_in,
                              void* d_out, int out_size, void* d_ws, size_t ws_size,
                              hipStream_t stream) {
  const float* feat1 = (const float*)d_in[0];
  const float* feat2 = (const float*)d_in[1];
  const float* memory = (const float*)d_in[2];
  float* out = (float*)d_out;

  char* ws = (char*)d_ws;
  size_t off = 0;
  auto wsalloc = [&](size_t bytes) {
    void* p = ws + off;
    off += (bytes + 255) & ~(size_t)255;
    return p;
  };

  u8* At = (u8*)wsalloc((size_t)NTILEA * NSLAB * SLB);   // 6.4 MB
  u8* Bt = (u8*)wsalloc((size_t)NTILEB * NSLAB * SLB);   // 20.6 MB
  float* mnorm = (float*)wsalloc((size_t)MEMN * 4);
  float* fnorm = (float*)wsalloc((size_t)NROWS * 4);
  unsigned int* minu = (unsigned int*)wsalloc((size_t)NROWS * 4);
  float* scores = (float*)wsalloc((size_t)NROWS * 4);
  // H2all aliases Bt: stream order guarantees feat_b_stage1/2 finish before memconv
  // overwrites Bt (3.2 MB << Bt's 20.6 MB).
  float* H2all = (float*)Bt;

  feat_a_fp8<<<(BQ * 64 * N1) / 256, 256, 0, stream>>>(feat1, At);
  feat_b_stage1<<<BQ * M2, 256, 0, stream>>>(feat2, H2all);
  feat_b_stage2_fp8<<<(BQ * 64 * N1) / 256, 256, 0, stream>>>(H2all, At);
  memconv_fp8<<<(NTILEB * NSLAB * 1024) / 256, 256, 0, stream>>>(memory, Bt);
  fnorm_fp8<<<NROWS / 4, 256, 0, stream>>>(At, fnorm);
  mnorm_fp8<<<MEMN, 256, 0, stream>>>(memory, mnorm);
  (void)hipMemsetAsync(minu, 0xFF, (size_t)NROWS * 4, stream);

  dist_min_mfma<<<NWG, 256, 0, stream>>>(At, Bt, mnorm, minu);

  scores_kernel<<<(NROWS + 255) / 256, 256, 0, stream>>>(fnorm, minu, scores);
  image_max_kernel<<<BQ, 256, 0, stream>>>(scores, out);
  upsample_kernel<<<(BQ * OUTHW + 255) / 256, 256, 0, stream>>>(scores, out);
}